// Round 3
// baseline (1250.331 us; speedup 1.0000x reference)
//
#include <hip/hip_runtime.h>
#include <hip/hip_bf16.h>

#define D 128

// ---------------- setup kernels ----------------

__global__ void k_zero(int* __restrict__ p, int n) {
    int i = blockIdx.x * 256 + threadIdx.x;
    if (i < n) p[i] = 0;
}

__global__ void k_count(const int* __restrict__ dst, int* __restrict__ cnt, int e) {
    int i = blockIdx.x * 256 + threadIdx.x;
    if (i < e) atomicAdd(&cnt[dst[i]], 1);
}

__global__ void k_dinv(const int* __restrict__ cnt, float* __restrict__ dinv, int n) {
    int i = blockIdx.x * 256 + threadIdx.x;
    if (i < n) {
        float deg = (float)(cnt[i] + 2);   // +2 = improved self-loop weight
        dinv[i] = 1.0f / sqrtf(deg);
    }
}

// ---- hierarchical scan: A) per-block reduce, B) scan partials, C) rescan ----

__global__ __launch_bounds__(256) void k_scanA(const int* __restrict__ cnt,
                                               int* __restrict__ partials, int n) {
    __shared__ int s[256];
    int b = blockIdx.x, t = threadIdx.x;
    int i0 = b * 512 + t * 2;
    int v = 0;
    if (i0 < n) v += cnt[i0];
    if (i0 + 1 < n) v += cnt[i0 + 1];
    s[t] = v;
    __syncthreads();
    for (int off = 128; off > 0; off >>= 1) {
        if (t < off) s[t] += s[t + off];
        __syncthreads();
    }
    if (t == 0) partials[b] = s[0];
}

__global__ __launch_bounds__(512) void k_scanB(const int* __restrict__ partials,
                                               int* __restrict__ base,
                                               int* __restrict__ off_n, int nb) {
    __shared__ int s[512];
    int t = threadIdx.x;
    int v = (t < nb) ? partials[t] : 0;
    s[t] = v;
    __syncthreads();
    for (int off = 1; off < 512; off <<= 1) {
        int x = (t >= off) ? s[t - off] : 0;
        __syncthreads();
        s[t] += x;
        __syncthreads();
    }
    if (t < nb) base[t] = s[t] - v;          // exclusive
    if (t == nb - 1) off_n[0] = s[t];        // total = offsets[N]
}

__global__ __launch_bounds__(256) void k_scanC(const int* __restrict__ cnt,
                                               const int* __restrict__ base,
                                               int* __restrict__ offsets,
                                               int* __restrict__ cursor, int n) {
    __shared__ int s[256];
    int b = blockIdx.x, t = threadIdx.x;
    int i0 = b * 512 + t * 2;
    int v0 = (i0 < n) ? cnt[i0] : 0;
    int v1 = (i0 + 1 < n) ? cnt[i0 + 1] : 0;
    int sum = v0 + v1;
    s[t] = sum;
    __syncthreads();
    for (int off = 1; off < 256; off <<= 1) {
        int x = (t >= off) ? s[t - off] : 0;
        __syncthreads();
        s[t] += x;
        __syncthreads();
    }
    int excl = s[t] - sum + base[b];
    if (i0 < n) { offsets[i0] = excl; cursor[i0] = excl; }
    if (i0 + 1 < n) { offsets[i0 + 1] = excl + v0; cursor[i0 + 1] = excl + v0; }
}

// packed CSR entry: .x = src node, .y = float bits of norm weight
__global__ void k_fill(const int* __restrict__ src, const int* __restrict__ dst,
                       int* __restrict__ cursor, const float* __restrict__ dinv,
                       int2* __restrict__ csr, int e) {
    int i = blockIdx.x * 256 + threadIdx.x;
    if (i < e) {
        int s = src[i];
        int d = dst[i];
        int pos = atomicAdd(&cursor[d], 1);
        float w = dinv[s] * dinv[d];
        csr[pos] = make_int2(s, __float_as_int(w));
    }
}

// ---------------- matmul: O[r][c] = sum_k H[r][k] * W[k][c] ----------------
__global__ __launch_bounds__(256) void k_matmul(const float* __restrict__ H,
                                                const float* __restrict__ W,
                                                float* __restrict__ O, int nrows) {
    __shared__ float Ws[32 * D];    // Ws[k][c]
    __shared__ float HsT[32 * D];   // HsT[k][r]
    const int t = threadIdx.x;
    const int row0 = blockIdx.x * 128;
    const int tx = t & 15;    // col group (8 cols)
    const int ty = t >> 4;    // row group (8 rows)

    float acc[8][8];
#pragma unroll
    for (int i = 0; i < 8; i++)
#pragma unroll
        for (int j = 0; j < 8; j++) acc[i][j] = 0.0f;

    const int r_st = t & 127;
    const int kb = (t >> 7) * 16;   // 0 or 16

    for (int kc = 0; kc < D; kc += 32) {
        {
            const float4* W4 = (const float4*)(W + kc * D);
            float4* Ws4 = (float4*)Ws;
#pragma unroll
            for (int it = 0; it < 4; it++) Ws4[t + it * 256] = W4[t + it * 256];
        }
        {
            int gr = row0 + r_st;
            float4 v0, v1, v2, v3;
            if (gr < nrows) {
                const float4* Hp = (const float4*)(H + (size_t)gr * D + kc + kb);
                v0 = Hp[0]; v1 = Hp[1]; v2 = Hp[2]; v3 = Hp[3];
            } else {
                v0 = v1 = v2 = v3 = make_float4(0.f, 0.f, 0.f, 0.f);
            }
            float vals[16];
            *(float4*)&vals[0]  = v0;
            *(float4*)&vals[4]  = v1;
            *(float4*)&vals[8]  = v2;
            *(float4*)&vals[12] = v3;
#pragma unroll
            for (int j = 0; j < 16; j++) HsT[(kb + j) * 128 + r_st] = vals[j];
        }
        __syncthreads();
#pragma unroll
        for (int k = 0; k < 32; k++) {
            float4 a0 = *(const float4*)&HsT[k * 128 + ty * 8];
            float4 a1 = *(const float4*)&HsT[k * 128 + ty * 8 + 4];
            float4 b0 = *(const float4*)&Ws[k * D + tx * 8];
            float4 b1 = *(const float4*)&Ws[k * D + tx * 8 + 4];
            float ar[8] = {a0.x, a0.y, a0.z, a0.w, a1.x, a1.y, a1.z, a1.w};
            float br[8] = {b0.x, b0.y, b0.z, b0.w, b1.x, b1.y, b1.z, b1.w};
#pragma unroll
            for (int i = 0; i < 8; i++)
#pragma unroll
                for (int j = 0; j < 8; j++) acc[i][j] += ar[i] * br[j];
        }
        __syncthreads();
    }
#pragma unroll
    for (int i = 0; i < 8; i++) {
        int gr = row0 + ty * 8 + i;
        if (gr < nrows) {
            float4* Op = (float4*)(O + (size_t)gr * D + tx * 8);
            Op[0] = make_float4(acc[i][0], acc[i][1], acc[i][2], acc[i][3]);
            Op[1] = make_float4(acc[i][4], acc[i][5], acc[i][6], acc[i][7]);
        }
    }
}

// ---------------- gather ----------------
// one wave per node; half-wave per edge (32 lanes x float4 = 512B row);
// 16 edges/group -> 8 independent dual-row loads in flight.
__global__ __launch_bounds__(256) void k_gather(const float* __restrict__ T,
                                                const int2* __restrict__ csr,
                                                const int* __restrict__ offsets,
                                                const float* __restrict__ dinv,
                                                const float* __restrict__ bias,
                                                float* __restrict__ O, int n) {
    int node = blockIdx.x * 4 + (threadIdx.x >> 6);
    if (node >= n) return;
    int lane = threadIdx.x & 63;
    int half = lane >> 5;            // 0 or 1
    int c = (lane & 31) << 2;        // col base (float4)
    const float* Tc = T + c;

    float ax = 0.f, ay = 0.f, az = 0.f, aw = 0.f;
    if (half == 0) {
        float di = dinv[node];
        float sw = 2.0f * di * di;
        float4 v = *(const float4*)(Tc + (size_t)node * D);
        ax = sw * v.x; ay = sw * v.y; az = sw * v.z; aw = sw * v.w;
    }

    int e = offsets[node];
    const int e1 = offsets[node + 1];

    // 16 edges per group: 8 independent dual-row loads
    for (; e + 16 <= e1; e += 16) {
        int2 c0 = csr[e + half],      c1 = csr[e + 2 + half];
        int2 c2 = csr[e + 4 + half],  c3 = csr[e + 6 + half];
        int2 c4 = csr[e + 8 + half],  c5 = csr[e + 10 + half];
        int2 c6 = csr[e + 12 + half], c7 = csr[e + 14 + half];
        float4 v0 = *(const float4*)(Tc + (size_t)c0.x * D);
        float4 v1 = *(const float4*)(Tc + (size_t)c1.x * D);
        float4 v2 = *(const float4*)(Tc + (size_t)c2.x * D);
        float4 v3 = *(const float4*)(Tc + (size_t)c3.x * D);
        float4 v4 = *(const float4*)(Tc + (size_t)c4.x * D);
        float4 v5 = *(const float4*)(Tc + (size_t)c5.x * D);
        float4 v6 = *(const float4*)(Tc + (size_t)c6.x * D);
        float4 v7 = *(const float4*)(Tc + (size_t)c7.x * D);
        float w0 = __int_as_float(c0.y), w1 = __int_as_float(c1.y);
        float w2 = __int_as_float(c2.y), w3 = __int_as_float(c3.y);
        float w4 = __int_as_float(c4.y), w5 = __int_as_float(c5.y);
        float w6 = __int_as_float(c6.y), w7 = __int_as_float(c7.y);
        ax += w0 * v0.x; ay += w0 * v0.y; az += w0 * v0.z; aw += w0 * v0.w;
        ax += w1 * v1.x; ay += w1 * v1.y; az += w1 * v1.z; aw += w1 * v1.w;
        ax += w2 * v2.x; ay += w2 * v2.y; az += w2 * v2.z; aw += w2 * v2.w;
        ax += w3 * v3.x; ay += w3 * v3.y; az += w3 * v3.z; aw += w3 * v3.w;
        ax += w4 * v4.x; ay += w4 * v4.y; az += w4 * v4.z; aw += w4 * v4.w;
        ax += w5 * v5.x; ay += w5 * v5.y; az += w5 * v5.z; aw += w5 * v5.w;
        ax += w6 * v6.x; ay += w6 * v6.y; az += w6 * v6.z; aw += w6 * v6.w;
        ax += w7 * v7.x; ay += w7 * v7.y; az += w7 * v7.z; aw += w7 * v7.w;
    }
    // 4 edges at a time (2 loads in flight)
    for (; e + 4 <= e1; e += 4) {
        int2 c0 = csr[e + half], c1 = csr[e + 2 + half];
        float4 v0 = *(const float4*)(Tc + (size_t)c0.x * D);
        float4 v1 = *(const float4*)(Tc + (size_t)c1.x * D);
        float w0 = __int_as_float(c0.y), w1 = __int_as_float(c1.y);
        ax += w0 * v0.x; ay += w0 * v0.y; az += w0 * v0.z; aw += w0 * v0.w;
        ax += w1 * v1.x; ay += w1 * v1.y; az += w1 * v1.z; aw += w1 * v1.w;
    }
    // 2 edges
    for (; e + 2 <= e1; e += 2) {
        int2 c0 = csr[e + half];
        float4 v0 = *(const float4*)(Tc + (size_t)c0.x * D);
        float w0 = __int_as_float(c0.y);
        ax += w0 * v0.x; ay += w0 * v0.y; az += w0 * v0.z; aw += w0 * v0.w;
    }
    // odd leftover: half 0 only
    if (e < e1 && half == 0) {
        int2 c0 = csr[e];
        float4 v0 = *(const float4*)(Tc + (size_t)c0.x * D);
        float w0 = __int_as_float(c0.y);
        ax += w0 * v0.x; ay += w0 * v0.y; az += w0 * v0.z; aw += w0 * v0.w;
    }

    // cross-half reduction
    ax += __shfl_xor(ax, 32, 64);
    ay += __shfl_xor(ay, 32, 64);
    az += __shfl_xor(az, 32, 64);
    aw += __shfl_xor(aw, 32, 64);

    if (half == 0) {
        const float4 b4 = *(const float4*)(bias + c);
        float4 r = make_float4(ax + b4.x, ay + b4.y, az + b4.z, aw + b4.w);
        *(float4*)(O + (size_t)node * D + c) = r;
    }
}

// ---------------- launch ----------------

extern "C" void kernel_launch(void* const* d_in, const int* in_sizes, int n_in,
                              void* d_out, int out_size, void* d_ws, size_t ws_size,
                              hipStream_t stream) {
    const float* x  = (const float*)d_in[0];
    const int*   ei = (const int*)d_in[1];
    const float* W1 = (const float*)d_in[2];
    const float* b1 = (const float*)d_in[3];
    const float* W2 = (const float*)d_in[4];
    const float* b2 = (const float*)d_in[5];
    const int N = in_sizes[0] / D;
    const int E = in_sizes[1] / 2;
    float* out = (float*)d_out;

    char* ws = (char*)d_ws;
    size_t woff = 0;
    auto alloc = [&](size_t bytes) -> void* {
        void* p = ws + woff;
        woff = (woff + bytes + 15) & ~(size_t)15;
        return p;
    };
    float* T        = (float*)alloc((size_t)N * D * sizeof(float));
    int*   cnt      = (int*)  alloc((size_t)N * sizeof(int));
    int*   offsets  = (int*)  alloc((size_t)(N + 1) * sizeof(int));
    int*   cursor   = (int*)  alloc((size_t)N * sizeof(int));
    float* dinv     = (float*)alloc((size_t)N * sizeof(float));
    int2*  csr      = (int2*) alloc((size_t)E * sizeof(int2));
    int*   partials = (int*)  alloc(1024 * sizeof(int));
    int*   base     = (int*)  alloc(1024 * sizeof(int));
    (void)ws_size; (void)n_in; (void)out_size;

    const int* e_src = ei;
    const int* e_dst = ei + E;
    const int NB = (N + 511) / 512;   // 196 <= 512

    k_zero<<<(N + 255) / 256, 256, 0, stream>>>(cnt, N);
    k_count<<<(E + 255) / 256, 256, 0, stream>>>(e_dst, cnt, E);
    k_dinv<<<(N + 255) / 256, 256, 0, stream>>>(cnt, dinv, N);
    k_scanA<<<NB, 256, 0, stream>>>(cnt, partials, N);
    k_scanB<<<1, 512, 0, stream>>>(partials, base, offsets + N, NB);
    k_scanC<<<NB, 256, 0, stream>>>(cnt, base, offsets, cursor, N);
    k_fill<<<(E + 255) / 256, 256, 0, stream>>>(e_src, e_dst, cursor, dinv, csr, E);

    const float* h = x;
    for (int l = 0; l < 5; l++) {
        const float* W = l ? W2 : W1;
        const float* b = l ? b2 : b1;
        k_matmul<<<(N + 127) / 128, 256, 0, stream>>>(h, W, T, N);
        k_gather<<<(N + 3) / 4, 256, 0, stream>>>(T, csr, offsets, dinv, b, out, N);
        h = out;
    }
}